// Round 5
// baseline (315.301 us; speedup 1.0000x reference)
//
#include <hip/hip_runtime.h>
#include <stdint.h>

#define CROWB 2816        // conv_out row bytes (1408 f16, K padded 1369->1408)
#define NOUT 40960
#define DGB 32832         // digit region base byte in conv smem
// digit layout: f16[i=28][s=10][36], elem = i*360 + s*36 + j (j<28 data, 28..35 zero)

typedef _Float16 f16x8 __attribute__((ext_vector_type(8)));
typedef float f32x4 __attribute__((ext_vector_type(4)));

// ---------------- threefry2x32 (key(1) -> (0,1)), partitionable path ------
#define TF_ROT(x, r) (((x) << (r)) | ((x) >> (32 - (r))))
#define TF_ROUND(r) { x0 += x1; x1 = TF_ROT(x1, (r)); x1 ^= x0; }

__device__ __forceinline__ float erfinv_f(float x) {
  float w = -log1pf(-x * x);
  float p;
  if (w < 5.0f) {
    w -= 2.5f;
    p = 2.81022636e-08f;
    p = fmaf(p, w, 3.43273939e-07f);
    p = fmaf(p, w, -3.5233877e-06f);
    p = fmaf(p, w, -4.39150654e-06f);
    p = fmaf(p, w, 0.00021858087f);
    p = fmaf(p, w, -0.00125372503f);
    p = fmaf(p, w, -0.00417768164f);
    p = fmaf(p, w, 0.246640727f);
    p = fmaf(p, w, 1.50140941f);
  } else {
    w = sqrtf(w) - 3.0f;
    p = -0.000200214257f;
    p = fmaf(p, w, 0.000100950558f);
    p = fmaf(p, w, 0.00134934322f);
    p = fmaf(p, w, -0.00367342844f);
    p = fmaf(p, w, 0.00573950773f);
    p = fmaf(p, w, -0.0076224613f);
    p = fmaf(p, w, 0.00943887047f);
    p = fmaf(p, w, 1.00167406f);
    p = fmaf(p, w, 2.83297682f);
  }
  return p * x;
}

__device__ __forceinline__ float gauss_eps(int p) {
  const unsigned ks0 = 0u, ks1 = 1u, ks2 = 0x1BD11BDBu;
  unsigned x0 = 0u + ks0;
  unsigned x1 = (unsigned)p + ks1;
  TF_ROUND(13) TF_ROUND(15) TF_ROUND(26) TF_ROUND(6)
  x0 += ks1; x1 += ks2 + 1u;
  TF_ROUND(17) TF_ROUND(29) TF_ROUND(16) TF_ROUND(24)
  x0 += ks2; x1 += ks0 + 2u;
  TF_ROUND(13) TF_ROUND(15) TF_ROUND(26) TF_ROUND(6)
  x0 += ks0; x1 += ks1 + 3u;
  TF_ROUND(17) TF_ROUND(29) TF_ROUND(16) TF_ROUND(24)
  x0 += ks1; x1 += ks2 + 4u;
  TF_ROUND(13) TF_ROUND(15) TF_ROUND(26) TF_ROUND(6)
  x0 += ks2; x1 += ks0 + 5u;
  unsigned bits = x0 ^ x1;
  unsigned fb = (bits >> 9) | 0x3f800000u;
  float f = __uint_as_float(fb) - 1.0f;
  const float lo = -0.99999994f;
  float u = f * 2.0f + lo;
  u = fmaxf(lo, u);
  return 1.41421356f * erfinv_f(u);
}

__device__ __forceinline__ float fast_tanh(float x) {
  float e = __expf(2.0f * x);
  return 1.0f - 2.0f * __builtin_amdgcn_rcpf(e + 1.0f);
}

__device__ __forceinline__ uint32_t packh2(float lo, float hi) {
  union { _Float16 h[2]; uint32_t u; } c;
  c.h[0] = (_Float16)lo; c.h[1] = (_Float16)hi;
  return c.u;
}

// ---------------- W1 transpose+f16 prep: w1t[h][k] (k padded to 1408) -----
// Thread tid owns output row h=tid for k-chunk [16*bx, 16*bx+16): the 16
// source reads are coalesced (256 threads x 4B), output is one 32B store.
__global__ __launch_bounds__(256) void prep_w1t(const float* __restrict__ W1,
                                                uint8_t* __restrict__ w1t) {
  int k0 = blockIdx.x * 16;
  int tid = threadIdx.x;
  float v[16];
  #pragma unroll
  for (int r = 0; r < 16; ++r) {
    int k = k0 + r;
    v[r] = (k < 1369) ? W1[(size_t)k * 256 + tid] : 0.0f;
  }
  uint32_t o[8];
  #pragma unroll
  for (int a = 0; a < 8; ++a) o[a] = packh2(v[2*a], v[2*a+1]);
  uint8_t* dst = w1t + (size_t)tid * CROWB + (size_t)k0 * 2;
  *(uint4*)(dst)      = make_uint4(o[0], o[1], o[2], o[3]);
  *(uint4*)(dst + 16) = make_uint4(o[4], o[5], o[6], o[7]);
}

// ---------------- stage 1: grouped correlation via MFMA -------------------
// Frame LDS layout: byte addr 8*e holds f16 elems {e, e+1, e+2, e+3}.
// Any 8-elem window at elem offset e0 = two aligned b64 reads (8e0, 8e0+32).
__global__ __launch_bounds__(256, 3) void conv_mfma(
    const float* __restrict__ frames, const float* __restrict__ digits,
    uint8_t* __restrict__ conv_out)
{
  // [0, 32832): frame slots (4104 slots x 8B); [32832, 52992): digits f16[28][10][36]
  __shared__ __align__(16) uint8_t smem[52992];
  const int g = blockIdx.x >> 4, t = blockIdx.x & 15;
  const int tid = threadIdx.x;
  const int lane = tid & 63, w = tid >> 6;
  const int l15 = lane & 15, lg = lane >> 4;
  const int jo = lg * 8;

  // ---- stage frames: thread owns elems [16*tid, 16*tid+16) ----
  {
    const float* fbase = frames + ((size_t)(g * 16 + t)) * 4096;
    float h[20];
    const float4* f4 = (const float4*)(fbase + tid * 16);
    #pragma unroll
    for (int a = 0; a < 4; ++a) {
      float4 v = f4[a];
      h[4*a] = v.x; h[4*a+1] = v.y; h[4*a+2] = v.z; h[4*a+3] = v.w;
    }
    float t0 = __shfl_down(h[0], 1), t1 = __shfl_down(h[1], 1),
          t2 = __shfl_down(h[2], 1), t3 = __shfl_down(h[3], 1);
    if (lane == 63) {
      int bidx = tid * 16 + 16;
      t0 = (bidx + 0 < 4096) ? fbase[bidx + 0] : 0.0f;
      t1 = (bidx + 1 < 4096) ? fbase[bidx + 1] : 0.0f;
      t2 = (bidx + 2 < 4096) ? fbase[bidx + 2] : 0.0f;
      t3 = (bidx + 3 < 4096) ? fbase[bidx + 3] : 0.0f;
    }
    h[16] = t0; h[17] = t1; h[18] = t2; h[19] = t3;
    #pragma unroll
    for (int c = 0; c < 8; ++c) {
      int cc = (c + tid) & 7;
      int le = 2 * cc;
      uint4 v;
      v.x = packh2(h[le],   h[le+1]);
      v.y = packh2(h[le+2], h[le+3]);
      v.z = packh2(h[le+1], h[le+2]);
      v.w = packh2(h[le+3], h[le+4]);
      *(uint4*)(smem + 128 * tid + 16 * cc) = v;
    }
    if (tid < 16) *(uint32_t*)(smem + 32768 + tid * 4) = 0u;
  }
  // ---- zero digit region (20160 B = 5040 dwords) ----
  {
    uint32_t* dz = (uint32_t*)(smem + DGB);
    for (int q = tid; q < 5040; q += 256) dz[q] = 0u;
  }
  __syncthreads();
  // ---- fill digits: [i][s][36] ----
  {
    const float* dsrc = digits + (size_t)g * 7840;
    for (int idx = tid; idx < 7840; idx += 256) {
      int s = idx / 784; int r = idx - s * 784;
      int i = r / 28;    int j = r - i * 28;
      *(_Float16*)(smem + DGB + (size_t)(i * 360 + s * 36 + j) * 2) = (_Float16)dsrc[idx];
    }
  }
  __syncthreads();

  // ---- per-lane A base addresses (byte = 8 * elem) for 22 m-tiles ----
  uint32_t abase[22];
  #pragma unroll
  for (int j2 = 0; j2 < 22; ++j2) {
    int tile = w + 4 * j2;
    int p = tile * 16 + l15;
    int py = p / 37, px = p - py * 37;
    abase[j2] = (uint32_t)(py * 64 + px + jo) * 8u;
  }
  // B base: lanes 10..15 clamp to s=0 (their C columns are never stored)
  const int s2 = (l15 < 10) ? l15 : 0;
  const uint32_t bbase = DGB + (uint32_t)(s2 * 36 + jo) * 2u;

  f32x4 acc[22];
  #pragma unroll
  for (int j2 = 0; j2 < 22; ++j2) acc[j2] = (f32x4){0.f, 0.f, 0.f, 0.f};

  for (int i = 0; i < 28; ++i) {
    f16x8 bfrag = *(const f16x8*)(smem + bbase + i * 720);
    #pragma unroll
    for (int j2 = 0; j2 < 22; ++j2) {
      const uint8_t* ap = smem + abase[j2] + i * 512;
      union { uint2 u2[2]; f16x8 v; } A;
      A.u2[0] = *(const uint2*)(ap);        // elems e0 .. e0+3
      A.u2[1] = *(const uint2*)(ap + 32);   // elems e0+4 .. e0+7
      acc[j2] = __builtin_amdgcn_mfma_f32_16x16x32_f16(A.v, bfrag, acc[j2], 0, 0, 0);
    }
  }

  // ---- C write: row m = t*1280 + 10g + s (s = l15), col k = p ----
  if (l15 < 10) {
    size_t rb = ((size_t)t * 1280 + 10 * g + l15) * (size_t)CROWB;
    #pragma unroll
    for (int j2 = 0; j2 < 22; ++j2) {
      int p0 = (w + 4 * j2) * 16 + lg * 4;
      #pragma unroll
      for (int r = 0; r < 4; ++r) {
        int p = p0 + r;
        if (p < 1369)
          *(_Float16*)(conv_out + rb + (size_t)p * 2) = (_Float16)acc[j2][r];
      }
    }
  }
}

// ---------------- stage 2+3: MFMA GEMM [80 x 1408] x [1408 x 256] + epi ---
// 256 blocks (1 per CU), 80 rows each; next-K-tile global loads are
// register-prefetched so load latency hides under the MFMA phase.
__global__ __launch_bounds__(256) void mlp_mfma(
    const uint8_t* __restrict__ conv_out, const uint8_t* __restrict__ w1t,
    const float* __restrict__ b1, const float* __restrict__ W2,
    const float* __restrict__ b2, const float* __restrict__ wstd,
    float* __restrict__ out)
{
  // A [0,10240): 80 rows x 128B swizzled; B [10240,43008): 256 x 128B; qb at 43008
  __shared__ __align__(16) uint8_t smem[45568];
  const int tid = threadIdx.x;
  const int lane = tid & 63, w = tid >> 6;
  const int l15 = lane & 15, lg = lane >> 4;
  const int m0 = blockIdx.x * 80;

  // per-thread staging coords
  int aR[3], ac16[3]; bool av[3];
  #pragma unroll
  for (int it = 0; it < 3; ++it) {
    int q = tid + 256 * it;
    av[it] = (q < 640); aR[it] = q >> 3; ac16[it] = q & 7;
  }
  int bR[8], bc16[8];
  #pragma unroll
  for (int it = 0; it < 8; ++it) {
    int q = tid + 256 * it;
    bR[it] = q >> 3; bc16[it] = q & 7;
  }

  f32x4 acc[5][4];
  #pragma unroll
  for (int mt = 0; mt < 5; ++mt)
    #pragma unroll
    for (int nj = 0; nj < 4; ++nj) acc[mt][nj] = (f32x4){0.f, 0.f, 0.f, 0.f};

  uint4 ra[3], rb[8];
  // prologue: load tile k0=0
  #pragma unroll
  for (int it = 0; it < 3; ++it)
    if (av[it]) ra[it] = *(const uint4*)(conv_out + (size_t)(m0 + aR[it]) * CROWB + ac16[it] * 16);
  #pragma unroll
  for (int it = 0; it < 8; ++it)
    rb[it] = *(const uint4*)(w1t + (size_t)bR[it] * CROWB + bc16[it] * 16);

  for (int k0 = 0; k0 < 1408; k0 += 64) {
    __syncthreads();   // previous tile's readers done
    #pragma unroll
    for (int it = 0; it < 3; ++it)
      if (av[it]) *(uint4*)(smem + aR[it] * 128 + ((ac16[it] * 16) ^ ((aR[it] & 7) << 4))) = ra[it];
    #pragma unroll
    for (int it = 0; it < 8; ++it)
      *(uint4*)(smem + 10240 + bR[it] * 128 + ((bc16[it] * 16) ^ ((bR[it] & 7) << 4))) = rb[it];
    __syncthreads();
    // prefetch next tile (overlaps with compute below)
    if (k0 + 64 < 1408) {
      #pragma unroll
      for (int it = 0; it < 3; ++it)
        if (av[it]) ra[it] = *(const uint4*)(conv_out + (size_t)(m0 + aR[it]) * CROWB + (size_t)(k0 + 64) * 2 + ac16[it] * 16);
      #pragma unroll
      for (int it = 0; it < 8; ++it)
        rb[it] = *(const uint4*)(w1t + (size_t)bR[it] * CROWB + (size_t)(k0 + 64) * 2 + bc16[it] * 16);
    }
    #pragma unroll
    for (int q = 0; q < 2; ++q) {
      f16x8 bf[4];
      #pragma unroll
      for (int nj = 0; nj < 4; ++nj) {
        int h = (w * 4 + nj) * 16 + l15;
        bf[nj] = *(const f16x8*)(smem + 10240 + h * 128 + ((q * 64 + lg * 16) ^ ((h & 7) << 4)));
      }
      #pragma unroll
      for (int mt = 0; mt < 5; ++mt) {
        int R = mt * 16 + l15;
        union { uint4 u; f16x8 v; } A;
        A.u = *(const uint4*)(smem + R * 128 + ((q * 64 + lg * 16) ^ ((R & 7) << 4)));
        #pragma unroll
        for (int nj = 0; nj < 4; ++nj)
          acc[mt][nj] = __builtin_amdgcn_mfma_f32_16x16x32_f16(A.v, bf[nj], acc[mt][nj], 0, 0, 0);
      }
    }
  }

  // ---- epilogue: tanh + tiny GEMM (H->2), cross-lane then cross-wave ----
  float qp[5][4][2];
  #pragma unroll
  for (int mt = 0; mt < 5; ++mt)
    #pragma unroll
    for (int r = 0; r < 4; ++r) { qp[mt][r][0] = 0.f; qp[mt][r][1] = 0.f; }

  #pragma unroll
  for (int nj = 0; nj < 4; ++nj) {
    int h = (w * 4 + nj) * 16 + l15;
    float bb = b1[h];
    float w20 = W2[2 * h], w21 = W2[2 * h + 1];
    #pragma unroll
    for (int mt = 0; mt < 5; ++mt)
      #pragma unroll
      for (int r = 0; r < 4; ++r) {
        float hid = fast_tanh(acc[mt][nj][r] + bb);
        qp[mt][r][0] = fmaf(hid, w20, qp[mt][r][0]);
        qp[mt][r][1] = fmaf(hid, w21, qp[mt][r][1]);
      }
  }
  #pragma unroll
  for (int off = 1; off <= 8; off <<= 1) {
    #pragma unroll
    for (int mt = 0; mt < 5; ++mt)
      #pragma unroll
      for (int r = 0; r < 4; ++r) {
        qp[mt][r][0] += __shfl_xor(qp[mt][r][0], off);
        qp[mt][r][1] += __shfl_xor(qp[mt][r][1], off);
      }
  }
  float* qb = (float*)(smem + 43008);
  if (l15 == 0) {
    #pragma unroll
    for (int mt = 0; mt < 5; ++mt)
      #pragma unroll
      for (int r = 0; r < 4; ++r) {
        int row = mt * 16 + lg * 4 + r;
        qb[(w * 80 + row) * 2 + 0] = qp[mt][r][0];
        qb[(w * 80 + row) * 2 + 1] = qp[mt][r][1];
      }
  }
  __syncthreads();
  if (tid < 160) {
    int row = tid >> 1, c = tid & 1;
    float sum = qb[row * 2 + c] + qb[(80 + row) * 2 + c] +
                qb[(160 + row) * 2 + c] + qb[(240 + row) * 2 + c];
    float q = fast_tanh(sum + b2[c]);
    int m = m0 + row;
    int tt = m / 1280;
    int o = m - tt * 1280;
    int base = (o * 16 + tt) * 2;
    out[base + c] = q;
    out[NOUT + base + c] = q + wstd[c] * gauss_eps(base + c);
  }
}

extern "C" void kernel_launch(void* const* d_in, const int* in_sizes, int n_in,
                              void* d_out, int out_size, void* d_ws, size_t ws_size,
                              hipStream_t stream) {
  const float* frames = (const float*)d_in[0];
  const float* digits = (const float*)d_in[1];
  const float* W1   = (const float*)d_in[3];
  const float* b1   = (const float*)d_in[4];
  const float* W2   = (const float*)d_in[5];
  const float* b2   = (const float*)d_in[6];
  const float* wstd = (const float*)d_in[7];
  uint8_t* conv_ws = (uint8_t*)d_ws;                          // [20480][2816B] f16
  uint8_t* w1t     = conv_ws + (size_t)20480 * CROWB;         // [256][2816B] f16
  float* out = (float*)d_out;

  prep_w1t<<<dim3(88), dim3(256), 0, stream>>>(W1, w1t);
  conv_mfma<<<dim3(2048), dim3(256), 0, stream>>>(frames, digits, conv_ws);
  mlp_mfma<<<dim3(256), dim3(256), 0, stream>>>(conv_ws, w1t, b1, W2, b2, wstd, out);
}

// Round 6
// 310.918 us; speedup vs baseline: 1.0141x; 1.0141x over previous
//
#include <hip/hip_runtime.h>
#include <stdint.h>

#define CROWB 2816        // conv_out row bytes (1408 f16, K padded 1369->1408)
#define NOUT 40960
#define DGB 32832         // digit region base byte in conv smem
// digit layout: f16[i=28][s=10][36], elem = i*360 + s*36 + j (j<28 data, 28..35 zero)

typedef _Float16 f16x8 __attribute__((ext_vector_type(8)));
typedef float f32x4 __attribute__((ext_vector_type(4)));

// ---------------- threefry2x32 (key(1) -> (0,1)), partitionable path ------
#define TF_ROT(x, r) (((x) << (r)) | ((x) >> (32 - (r))))
#define TF_ROUND(r) { x0 += x1; x1 = TF_ROT(x1, (r)); x1 ^= x0; }

__device__ __forceinline__ float erfinv_f(float x) {
  float w = -log1pf(-x * x);
  float p;
  if (w < 5.0f) {
    w -= 2.5f;
    p = 2.81022636e-08f;
    p = fmaf(p, w, 3.43273939e-07f);
    p = fmaf(p, w, -3.5233877e-06f);
    p = fmaf(p, w, -4.39150654e-06f);
    p = fmaf(p, w, 0.00021858087f);
    p = fmaf(p, w, -0.00125372503f);
    p = fmaf(p, w, -0.00417768164f);
    p = fmaf(p, w, 0.246640727f);
    p = fmaf(p, w, 1.50140941f);
  } else {
    w = sqrtf(w) - 3.0f;
    p = -0.000200214257f;
    p = fmaf(p, w, 0.000100950558f);
    p = fmaf(p, w, 0.00134934322f);
    p = fmaf(p, w, -0.00367342844f);
    p = fmaf(p, w, 0.00573950773f);
    p = fmaf(p, w, -0.0076224613f);
    p = fmaf(p, w, 0.00943887047f);
    p = fmaf(p, w, 1.00167406f);
    p = fmaf(p, w, 2.83297682f);
  }
  return p * x;
}

__device__ __forceinline__ float gauss_eps(int p) {
  const unsigned ks0 = 0u, ks1 = 1u, ks2 = 0x1BD11BDBu;
  unsigned x0 = 0u + ks0;
  unsigned x1 = (unsigned)p + ks1;
  TF_ROUND(13) TF_ROUND(15) TF_ROUND(26) TF_ROUND(6)
  x0 += ks1; x1 += ks2 + 1u;
  TF_ROUND(17) TF_ROUND(29) TF_ROUND(16) TF_ROUND(24)
  x0 += ks2; x1 += ks0 + 2u;
  TF_ROUND(13) TF_ROUND(15) TF_ROUND(26) TF_ROUND(6)
  x0 += ks0; x1 += ks1 + 3u;
  TF_ROUND(17) TF_ROUND(29) TF_ROUND(16) TF_ROUND(24)
  x0 += ks1; x1 += ks2 + 4u;
  TF_ROUND(13) TF_ROUND(15) TF_ROUND(26) TF_ROUND(6)
  x0 += ks2; x1 += ks0 + 5u;
  unsigned bits = x0 ^ x1;
  unsigned fb = (bits >> 9) | 0x3f800000u;
  float f = __uint_as_float(fb) - 1.0f;
  const float lo = -0.99999994f;
  float u = f * 2.0f + lo;
  u = fmaxf(lo, u);
  return 1.41421356f * erfinv_f(u);
}

__device__ __forceinline__ float fast_tanh(float x) {
  float e = __expf(2.0f * x);
  return 1.0f - 2.0f * __builtin_amdgcn_rcpf(e + 1.0f);
}

__device__ __forceinline__ uint32_t packh2(float lo, float hi) {
  union { _Float16 h[2]; uint32_t u; } c;
  c.h[0] = (_Float16)lo; c.h[1] = (_Float16)hi;
  return c.u;
}

// ---------------- W1 transpose+f16 prep: w1t[h][k] (k padded to 1408) -----
__global__ __launch_bounds__(256) void prep_w1t(const float* __restrict__ W1,
                                                uint8_t* __restrict__ w1t) {
  int k0 = blockIdx.x * 16;
  int tid = threadIdx.x;
  float v[16];
  #pragma unroll
  for (int r = 0; r < 16; ++r) {
    int k = k0 + r;
    v[r] = (k < 1369) ? W1[(size_t)k * 256 + tid] : 0.0f;
  }
  uint32_t o[8];
  #pragma unroll
  for (int a = 0; a < 8; ++a) o[a] = packh2(v[2*a], v[2*a+1]);
  uint8_t* dst = w1t + (size_t)tid * CROWB + (size_t)k0 * 2;
  *(uint4*)(dst)      = make_uint4(o[0], o[1], o[2], o[3]);
  *(uint4*)(dst + 16) = make_uint4(o[4], o[5], o[6], o[7]);
}

// ---------------- stage 1: grouped correlation via MFMA (round-5, kept) ---
__global__ __launch_bounds__(256, 3) void conv_mfma(
    const float* __restrict__ frames, const float* __restrict__ digits,
    uint8_t* __restrict__ conv_out)
{
  __shared__ __align__(16) uint8_t smem[52992];
  const int g = blockIdx.x >> 4, t = blockIdx.x & 15;
  const int tid = threadIdx.x;
  const int lane = tid & 63, w = tid >> 6;
  const int l15 = lane & 15, lg = lane >> 4;
  const int jo = lg * 8;

  {
    const float* fbase = frames + ((size_t)(g * 16 + t)) * 4096;
    float h[20];
    const float4* f4 = (const float4*)(fbase + tid * 16);
    #pragma unroll
    for (int a = 0; a < 4; ++a) {
      float4 v = f4[a];
      h[4*a] = v.x; h[4*a+1] = v.y; h[4*a+2] = v.z; h[4*a+3] = v.w;
    }
    float t0 = __shfl_down(h[0], 1), t1 = __shfl_down(h[1], 1),
          t2 = __shfl_down(h[2], 1), t3 = __shfl_down(h[3], 1);
    if (lane == 63) {
      int bidx = tid * 16 + 16;
      t0 = (bidx + 0 < 4096) ? fbase[bidx + 0] : 0.0f;
      t1 = (bidx + 1 < 4096) ? fbase[bidx + 1] : 0.0f;
      t2 = (bidx + 2 < 4096) ? fbase[bidx + 2] : 0.0f;
      t3 = (bidx + 3 < 4096) ? fbase[bidx + 3] : 0.0f;
    }
    h[16] = t0; h[17] = t1; h[18] = t2; h[19] = t3;
    #pragma unroll
    for (int c = 0; c < 8; ++c) {
      int cc = (c + tid) & 7;
      int le = 2 * cc;
      uint4 v;
      v.x = packh2(h[le],   h[le+1]);
      v.y = packh2(h[le+2], h[le+3]);
      v.z = packh2(h[le+1], h[le+2]);
      v.w = packh2(h[le+3], h[le+4]);
      *(uint4*)(smem + 128 * tid + 16 * cc) = v;
    }
    if (tid < 16) *(uint32_t*)(smem + 32768 + tid * 4) = 0u;
  }
  {
    uint32_t* dz = (uint32_t*)(smem + DGB);
    for (int q = tid; q < 5040; q += 256) dz[q] = 0u;
  }
  __syncthreads();
  {
    const float* dsrc = digits + (size_t)g * 7840;
    for (int idx = tid; idx < 7840; idx += 256) {
      int s = idx / 784; int r = idx - s * 784;
      int i = r / 28;    int j = r - i * 28;
      *(_Float16*)(smem + DGB + (size_t)(i * 360 + s * 36 + j) * 2) = (_Float16)dsrc[idx];
    }
  }
  __syncthreads();

  uint32_t abase[22];
  #pragma unroll
  for (int j2 = 0; j2 < 22; ++j2) {
    int tile = w + 4 * j2;
    int p = tile * 16 + l15;
    int py = p / 37, px = p - py * 37;
    abase[j2] = (uint32_t)(py * 64 + px + jo) * 8u;
  }
  const int s2 = (l15 < 10) ? l15 : 0;
  const uint32_t bbase = DGB + (uint32_t)(s2 * 36 + jo) * 2u;

  f32x4 acc[22];
  #pragma unroll
  for (int j2 = 0; j2 < 22; ++j2) acc[j2] = (f32x4){0.f, 0.f, 0.f, 0.f};

  for (int i = 0; i < 28; ++i) {
    f16x8 bfrag = *(const f16x8*)(smem + bbase + i * 720);
    #pragma unroll
    for (int j2 = 0; j2 < 22; ++j2) {
      const uint8_t* ap = smem + abase[j2] + i * 512;
      union { uint2 u2[2]; f16x8 v; } A;
      A.u2[0] = *(const uint2*)(ap);
      A.u2[1] = *(const uint2*)(ap + 32);
      acc[j2] = __builtin_amdgcn_mfma_f32_16x16x32_f16(A.v, bfrag, acc[j2], 0, 0, 0);
    }
  }

  if (l15 < 10) {
    size_t rb = ((size_t)t * 1280 + 10 * g + l15) * (size_t)CROWB;
    #pragma unroll
    for (int j2 = 0; j2 < 22; ++j2) {
      int p0 = (w + 4 * j2) * 16 + lg * 4;
      #pragma unroll
      for (int r = 0; r < 4; ++r) {
        int p = p0 + r;
        if (p < 1369)
          *(_Float16*)(conv_out + rb + (size_t)p * 2) = (_Float16)acc[j2][r];
      }
    }
  }
}

// ---------------- stage 2+3: MFMA GEMM [80x1408]x[1408x256], 8 waves ------
// 256 blocks (1/CU), 512 threads. BK=32, double-buffered LDS, one barrier
// per iter, depth-1 register prefetch issued before the compute phase.
// LDS rows padded to 80 B (20-dword stride -> conflict-light, no XOR).
#define ABUF 6400          // 80 rows x 80 B
#define BBUF 20480         // 256 rows x 80 B
#define BBASE0 12800       // 2*ABUF
#define QBOFF 53760        // 2*ABUF + 2*BBUF
__global__ __launch_bounds__(512) void mlp_mfma(
    const uint8_t* __restrict__ conv_out, const uint8_t* __restrict__ w1t,
    const float* __restrict__ b1, const float* __restrict__ W2,
    const float* __restrict__ b2, const float* __restrict__ wstd,
    float* __restrict__ out)
{
  __shared__ __align__(16) uint8_t smem[58880];
  const int tid = threadIdx.x;
  const int lane = tid & 63, w = tid >> 6;
  const int l15 = lane & 15, lg = lane >> 4;
  const int m0 = blockIdx.x * 80;

  // ---- staging slots: 320 A uint4 + 1024 B uint4 over 512 threads x 3 ----
  int soff[3];               // LDS byte offset for buffer-pair 0 (-1 = idle)
  int sbump[3];              // add for buffer-pair 1
  const uint8_t* sg[3];      // global source base (k=0)
  #pragma unroll
  for (int it = 0; it < 3; ++it) {
    int q = tid + 512 * it;
    if (q < 320) {
      int R = q >> 2, c = q & 3;
      soff[it] = R * 80 + c * 16;
      sbump[it] = ABUF;
      sg[it] = conv_out + (size_t)(m0 + R) * CROWB + c * 16;
    } else if (q < 1344) {
      int q2 = q - 320; int h = q2 >> 2, c = q2 & 3;
      soff[it] = BBASE0 + h * 80 + c * 16;
      sbump[it] = BBUF;
      sg[it] = w1t + (size_t)h * CROWB + c * 16;
    } else {
      soff[it] = -1; sbump[it] = 0; sg[it] = conv_out;
    }
  }

  f32x4 acc[5][2];
  #pragma unroll
  for (int mt = 0; mt < 5; ++mt) {
    acc[mt][0] = (f32x4){0.f, 0.f, 0.f, 0.f};
    acc[mt][1] = (f32x4){0.f, 0.f, 0.f, 0.f};
  }

  uint4 rg[3];
  // prologue: tile 0
  #pragma unroll
  for (int it = 0; it < 3; ++it)
    if (soff[it] >= 0) rg[it] = *(const uint4*)(sg[it]);
  #pragma unroll
  for (int it = 0; it < 3; ++it)
    if (soff[it] >= 0) *(uint4*)(smem + soff[it]) = rg[it];
  __syncthreads();

  for (int kt = 0; kt < 44; ++kt) {
    const int cur = kt & 1;
    const bool more = (kt + 1 < 44);
    // issue next-tile loads first (latency hides under compute)
    if (more) {
      #pragma unroll
      for (int it = 0; it < 3; ++it)
        if (soff[it] >= 0) rg[it] = *(const uint4*)(sg[it] + (size_t)(kt + 1) * 64);
    }
    // compute from buf[cur]
    {
      const uint8_t* aB = smem + (cur ? ABUF : 0);
      const uint8_t* bB = smem + BBASE0 + (cur ? BBUF : 0);
      f16x8 bf[2];
      #pragma unroll
      for (int nj = 0; nj < 2; ++nj) {
        int h = (w * 2 + nj) * 16 + l15;
        bf[nj] = *(const f16x8*)(bB + h * 80 + lg * 16);
      }
      #pragma unroll
      for (int mt = 0; mt < 5; ++mt) {
        int R = mt * 16 + l15;
        union { uint4 u; f16x8 v; } A;
        A.u = *(const uint4*)(aB + R * 80 + lg * 16);
        acc[mt][0] = __builtin_amdgcn_mfma_f32_16x16x32_f16(A.v, bf[0], acc[mt][0], 0, 0, 0);
        acc[mt][1] = __builtin_amdgcn_mfma_f32_16x16x32_f16(A.v, bf[1], acc[mt][1], 0, 0, 0);
      }
    }
    // write next tile into the other buffer (vmcnt wait auto-inserted)
    if (more) {
      int nxt = (kt + 1) & 1;
      #pragma unroll
      for (int it = 0; it < 3; ++it)
        if (soff[it] >= 0) *(uint4*)(smem + soff[it] + (nxt ? sbump[it] : 0)) = rg[it];
    }
    __syncthreads();
  }

  // ---- epilogue: tanh + H->2 GEMM; reduce over l15, then over waves ----
  float qp[5][4][2];
  #pragma unroll
  for (int mt = 0; mt < 5; ++mt)
    #pragma unroll
    for (int r = 0; r < 4; ++r) { qp[mt][r][0] = 0.f; qp[mt][r][1] = 0.f; }

  #pragma unroll
  for (int nj = 0; nj < 2; ++nj) {
    int h = (w * 2 + nj) * 16 + l15;
    float bb = b1[h];
    float w20 = W2[2 * h], w21 = W2[2 * h + 1];
    #pragma unroll
    for (int mt = 0; mt < 5; ++mt)
      #pragma unroll
      for (int r = 0; r < 4; ++r) {
        float hid = fast_tanh(acc[mt][nj][r] + bb);
        qp[mt][r][0] = fmaf(hid, w20, qp[mt][r][0]);
        qp[mt][r][1] = fmaf(hid, w21, qp[mt][r][1]);
      }
  }
  #pragma unroll
  for (int off = 1; off <= 8; off <<= 1) {
    #pragma unroll
    for (int mt = 0; mt < 5; ++mt)
      #pragma unroll
      for (int r = 0; r < 4; ++r) {
        qp[mt][r][0] += __shfl_xor(qp[mt][r][0], off);
        qp[mt][r][1] += __shfl_xor(qp[mt][r][1], off);
      }
  }
  float* qb = (float*)(smem + QBOFF);    // [8][80][2]
  if (l15 == 0) {
    #pragma unroll
    for (int mt = 0; mt < 5; ++mt)
      #pragma unroll
      for (int r = 0; r < 4; ++r) {
        int row = mt * 16 + lg * 4 + r;
        qb[(w * 80 + row) * 2 + 0] = qp[mt][r][0];
        qb[(w * 80 + row) * 2 + 1] = qp[mt][r][1];
      }
  }
  __syncthreads();
  if (tid < 160) {
    int row = tid >> 1, c = tid & 1;
    float sum = 0.f;
    #pragma unroll
    for (int ww = 0; ww < 8; ++ww) sum += qb[(ww * 80 + row) * 2 + c];
    float q = fast_tanh(sum + b2[c]);
    int m = m0 + row;
    int tt = m / 1280;
    int o = m - tt * 1280;
    int base = (o * 16 + tt) * 2;
    out[base + c] = q;
    out[NOUT + base + c] = q + wstd[c] * gauss_eps(base + c);
  }
}

extern "C" void kernel_launch(void* const* d_in, const int* in_sizes, int n_in,
                              void* d_out, int out_size, void* d_ws, size_t ws_size,
                              hipStream_t stream) {
  const float* frames = (const float*)d_in[0];
  const float* digits = (const float*)d_in[1];
  const float* W1   = (const float*)d_in[3];
  const float* b1   = (const float*)d_in[4];
  const float* W2   = (const float*)d_in[5];
  const float* b2   = (const float*)d_in[6];
  const float* wstd = (const float*)d_in[7];
  uint8_t* conv_ws = (uint8_t*)d_ws;                          // [20480][2816B] f16
  uint8_t* w1t     = conv_ws + (size_t)20480 * CROWB;         // [256][2816B] f16
  float* out = (float*)d_out;

  prep_w1t<<<dim3(88), dim3(256), 0, stream>>>(W1, w1t);
  conv_mfma<<<dim3(2048), dim3(256), 0, stream>>>(frames, digits, conv_ws);
  mlp_mfma<<<dim3(256), dim3(512), 0, stream>>>(conv_ws, w1t, b1, W2, b2, wstd, out);
}

// Round 7
// 260.330 us; speedup vs baseline: 1.2112x; 1.1943x over previous
//
#include <hip/hip_runtime.h>
#include <stdint.h>

#define CROWB 2816        // conv_out row bytes (1408 f16, K padded 1369->1408)
#define NOUT 40960
#define DGB 32832         // digit region base byte in conv smem
// digit layout: f16[i=28][s=10][36], elem = i*360 + s*36 + j (j<28 data, 28..35 zero)

typedef _Float16 f16x8 __attribute__((ext_vector_type(8)));
typedef float f32x4 __attribute__((ext_vector_type(4)));

// ---------------- threefry2x32 (key(1) -> (0,1)), partitionable path ------
#define TF_ROT(x, r) (((x) << (r)) | ((x) >> (32 - (r))))
#define TF_ROUND(r) { x0 += x1; x1 = TF_ROT(x1, (r)); x1 ^= x0; }

__device__ __forceinline__ float erfinv_f(float x) {
  float w = -log1pf(-x * x);
  float p;
  if (w < 5.0f) {
    w -= 2.5f;
    p = 2.81022636e-08f;
    p = fmaf(p, w, 3.43273939e-07f);
    p = fmaf(p, w, -3.5233877e-06f);
    p = fmaf(p, w, -4.39150654e-06f);
    p = fmaf(p, w, 0.00021858087f);
    p = fmaf(p, w, -0.00125372503f);
    p = fmaf(p, w, -0.00417768164f);
    p = fmaf(p, w, 0.246640727f);
    p = fmaf(p, w, 1.50140941f);
  } else {
    w = sqrtf(w) - 3.0f;
    p = -0.000200214257f;
    p = fmaf(p, w, 0.000100950558f);
    p = fmaf(p, w, 0.00134934322f);
    p = fmaf(p, w, -0.00367342844f);
    p = fmaf(p, w, 0.00573950773f);
    p = fmaf(p, w, -0.0076224613f);
    p = fmaf(p, w, 0.00943887047f);
    p = fmaf(p, w, 1.00167406f);
    p = fmaf(p, w, 2.83297682f);
  }
  return p * x;
}

__device__ __forceinline__ float gauss_eps(int p) {
  const unsigned ks0 = 0u, ks1 = 1u, ks2 = 0x1BD11BDBu;
  unsigned x0 = 0u + ks0;
  unsigned x1 = (unsigned)p + ks1;
  TF_ROUND(13) TF_ROUND(15) TF_ROUND(26) TF_ROUND(6)
  x0 += ks1; x1 += ks2 + 1u;
  TF_ROUND(17) TF_ROUND(29) TF_ROUND(16) TF_ROUND(24)
  x0 += ks2; x1 += ks0 + 2u;
  TF_ROUND(13) TF_ROUND(15) TF_ROUND(26) TF_ROUND(6)
  x0 += ks0; x1 += ks1 + 3u;
  TF_ROUND(17) TF_ROUND(29) TF_ROUND(16) TF_ROUND(24)
  x0 += ks1; x1 += ks2 + 4u;
  TF_ROUND(13) TF_ROUND(15) TF_ROUND(26) TF_ROUND(6)
  x0 += ks2; x1 += ks0 + 5u;
  unsigned bits = x0 ^ x1;
  unsigned fb = (bits >> 9) | 0x3f800000u;
  float f = __uint_as_float(fb) - 1.0f;
  const float lo = -0.99999994f;
  float u = f * 2.0f + lo;
  u = fmaxf(lo, u);
  return 1.41421356f * erfinv_f(u);
}

__device__ __forceinline__ float fast_tanh(float x) {
  float e = __expf(2.0f * x);
  return 1.0f - 2.0f * __builtin_amdgcn_rcpf(e + 1.0f);
}

__device__ __forceinline__ uint32_t packh2(float lo, float hi) {
  union { _Float16 h[2]; uint32_t u; } c;
  c.h[0] = (_Float16)lo; c.h[1] = (_Float16)hi;
  return c.u;
}

// ---------------- W1 transpose+f16 prep: w1t[h][k] (k padded to 1408) -----
__global__ __launch_bounds__(256) void prep_w1t(const float* __restrict__ W1,
                                                uint8_t* __restrict__ w1t) {
  int k0 = blockIdx.x * 16;
  int tid = threadIdx.x;
  float v[16];
  #pragma unroll
  for (int r = 0; r < 16; ++r) {
    int k = k0 + r;
    v[r] = (k < 1369) ? W1[(size_t)k * 256 + tid] : 0.0f;
  }
  uint32_t o[8];
  #pragma unroll
  for (int a = 0; a < 8; ++a) o[a] = packh2(v[2*a], v[2*a+1]);
  uint8_t* dst = w1t + (size_t)tid * CROWB + (size_t)k0 * 2;
  *(uint4*)(dst)      = make_uint4(o[0], o[1], o[2], o[3]);
  *(uint4*)(dst + 16) = make_uint4(o[4], o[5], o[6], o[7]);
}

// ---------------- stage 1: grouped correlation via MFMA (round-5, kept) ---
__global__ __launch_bounds__(256, 3) void conv_mfma(
    const float* __restrict__ frames, const float* __restrict__ digits,
    uint8_t* __restrict__ conv_out)
{
  __shared__ __align__(16) uint8_t smem[52992];
  const int g = blockIdx.x >> 4, t = blockIdx.x & 15;
  const int tid = threadIdx.x;
  const int lane = tid & 63, w = tid >> 6;
  const int l15 = lane & 15, lg = lane >> 4;
  const int jo = lg * 8;

  {
    const float* fbase = frames + ((size_t)(g * 16 + t)) * 4096;
    float h[20];
    const float4* f4 = (const float4*)(fbase + tid * 16);
    #pragma unroll
    for (int a = 0; a < 4; ++a) {
      float4 v = f4[a];
      h[4*a] = v.x; h[4*a+1] = v.y; h[4*a+2] = v.z; h[4*a+3] = v.w;
    }
    float t0 = __shfl_down(h[0], 1), t1 = __shfl_down(h[1], 1),
          t2 = __shfl_down(h[2], 1), t3 = __shfl_down(h[3], 1);
    if (lane == 63) {
      int bidx = tid * 16 + 16;
      t0 = (bidx + 0 < 4096) ? fbase[bidx + 0] : 0.0f;
      t1 = (bidx + 1 < 4096) ? fbase[bidx + 1] : 0.0f;
      t2 = (bidx + 2 < 4096) ? fbase[bidx + 2] : 0.0f;
      t3 = (bidx + 3 < 4096) ? fbase[bidx + 3] : 0.0f;
    }
    h[16] = t0; h[17] = t1; h[18] = t2; h[19] = t3;
    #pragma unroll
    for (int c = 0; c < 8; ++c) {
      int cc = (c + tid) & 7;
      int le = 2 * cc;
      uint4 v;
      v.x = packh2(h[le],   h[le+1]);
      v.y = packh2(h[le+2], h[le+3]);
      v.z = packh2(h[le+1], h[le+2]);
      v.w = packh2(h[le+3], h[le+4]);
      *(uint4*)(smem + 128 * tid + 16 * cc) = v;
    }
    if (tid < 16) *(uint32_t*)(smem + 32768 + tid * 4) = 0u;
  }
  {
    uint32_t* dz = (uint32_t*)(smem + DGB);
    for (int q = tid; q < 5040; q += 256) dz[q] = 0u;
  }
  __syncthreads();
  {
    const float* dsrc = digits + (size_t)g * 7840;
    for (int idx = tid; idx < 7840; idx += 256) {
      int s = idx / 784; int r = idx - s * 784;
      int i = r / 28;    int j = r - i * 28;
      *(_Float16*)(smem + DGB + (size_t)(i * 360 + s * 36 + j) * 2) = (_Float16)dsrc[idx];
    }
  }
  __syncthreads();

  uint32_t abase[22];
  #pragma unroll
  for (int j2 = 0; j2 < 22; ++j2) {
    int tile = w + 4 * j2;
    int p = tile * 16 + l15;
    int py = p / 37, px = p - py * 37;
    abase[j2] = (uint32_t)(py * 64 + px + jo) * 8u;
  }
  const int s2 = (l15 < 10) ? l15 : 0;
  const uint32_t bbase = DGB + (uint32_t)(s2 * 36 + jo) * 2u;

  f32x4 acc[22];
  #pragma unroll
  for (int j2 = 0; j2 < 22; ++j2) acc[j2] = (f32x4){0.f, 0.f, 0.f, 0.f};

  for (int i = 0; i < 28; ++i) {
    f16x8 bfrag = *(const f16x8*)(smem + bbase + i * 720);
    #pragma unroll
    for (int j2 = 0; j2 < 22; ++j2) {
      const uint8_t* ap = smem + abase[j2] + i * 512;
      union { uint2 u2[2]; f16x8 v; } A;
      A.u2[0] = *(const uint2*)(ap);
      A.u2[1] = *(const uint2*)(ap + 32);
      acc[j2] = __builtin_amdgcn_mfma_f32_16x16x32_f16(A.v, bfrag, acc[j2], 0, 0, 0);
    }
  }

  if (l15 < 10) {
    size_t rb = ((size_t)t * 1280 + 10 * g + l15) * (size_t)CROWB;
    #pragma unroll
    for (int j2 = 0; j2 < 22; ++j2) {
      int p0 = (w + 4 * j2) * 16 + lg * 4;
      #pragma unroll
      for (int r = 0; r < 4; ++r) {
        int p = p0 + r;
        if (p < 1369)
          *(_Float16*)(conv_out + rb + (size_t)p * 2) = (_Float16)acc[j2][r];
      }
    }
  }
}

// ---------------- stage 2+3: MFMA GEMM [32 x 1408] x [1408 x 256] + epi ---
// 640 blocks x 256 threads (32 rows each), BK=64, XOR-swizzled LDS,
// no register prefetch; 2-3 resident blocks/CU provide cross-block overlap.
__global__ __launch_bounds__(256) void mlp_mfma(
    const uint8_t* __restrict__ conv_out, const uint8_t* __restrict__ w1t,
    const float* __restrict__ b1, const float* __restrict__ W2,
    const float* __restrict__ b2, const float* __restrict__ wstd,
    float* __restrict__ out)
{
  // A [0,4096): 32 rows x 128B swizzled; B [4096,36864): 256 x 128B; qb at 36864
  __shared__ __align__(16) uint8_t smem[37888];
  const int tid = threadIdx.x;
  const int lane = tid & 63, w = tid >> 6;
  const int l15 = lane & 15, lg = lane >> 4;
  const int m0 = blockIdx.x * 32;

  f32x4 acc[2][4];
  #pragma unroll
  for (int mt = 0; mt < 2; ++mt)
    #pragma unroll
    for (int nj = 0; nj < 4; ++nj) acc[mt][nj] = (f32x4){0.f, 0.f, 0.f, 0.f};

  const int aR = tid >> 3, ac16 = tid & 7;

  for (int k0 = 0; k0 < 1408; k0 += 64) {
    __syncthreads();
    { // stage A: 32 rows x 128B (1 uint4 per thread)
      uint4 v = *(const uint4*)(conv_out + (size_t)(m0 + aR) * CROWB + (size_t)k0 * 2 + ac16 * 16);
      *(uint4*)(smem + aR * 128 + ((ac16 * 16) ^ ((aR & 7) << 4))) = v;
    }
    #pragma unroll
    for (int it = 0; it < 8; ++it) { // stage B: 256 rows x 128B
      int q = tid + 256 * it; int h = q >> 3, c16 = q & 7;
      uint4 v = *(const uint4*)(w1t + (size_t)h * CROWB + (size_t)k0 * 2 + c16 * 16);
      *(uint4*)(smem + 4096 + h * 128 + ((c16 * 16) ^ ((h & 7) << 4))) = v;
    }
    __syncthreads();
    #pragma unroll
    for (int q = 0; q < 2; ++q) {
      f16x8 bf[4];
      #pragma unroll
      for (int nj = 0; nj < 4; ++nj) {
        int h = (w * 4 + nj) * 16 + l15;
        bf[nj] = *(const f16x8*)(smem + 4096 + h * 128 + ((q * 64 + lg * 16) ^ ((h & 7) << 4)));
      }
      #pragma unroll
      for (int mt = 0; mt < 2; ++mt) {
        int R = mt * 16 + l15;
        union { uint4 u; f16x8 v; } A;
        A.u = *(const uint4*)(smem + R * 128 + ((q * 64 + lg * 16) ^ ((R & 7) << 4)));
        #pragma unroll
        for (int nj = 0; nj < 4; ++nj)
          acc[mt][nj] = __builtin_amdgcn_mfma_f32_16x16x32_f16(A.v, bf[nj], acc[mt][nj], 0, 0, 0);
      }
    }
  }

  // ---- epilogue: tanh + H->2 GEMM; reduce over l15, then over waves ----
  float qp[2][4][2];
  #pragma unroll
  for (int mt = 0; mt < 2; ++mt)
    #pragma unroll
    for (int r = 0; r < 4; ++r) { qp[mt][r][0] = 0.f; qp[mt][r][1] = 0.f; }

  #pragma unroll
  for (int nj = 0; nj < 4; ++nj) {
    int h = (w * 4 + nj) * 16 + l15;
    float bb = b1[h];
    float w20 = W2[2 * h], w21 = W2[2 * h + 1];
    #pragma unroll
    for (int mt = 0; mt < 2; ++mt)
      #pragma unroll
      for (int r = 0; r < 4; ++r) {
        float hid = fast_tanh(acc[mt][nj][r] + bb);
        qp[mt][r][0] = fmaf(hid, w20, qp[mt][r][0]);
        qp[mt][r][1] = fmaf(hid, w21, qp[mt][r][1]);
      }
  }
  #pragma unroll
  for (int off = 1; off <= 8; off <<= 1) {
    #pragma unroll
    for (int mt = 0; mt < 2; ++mt)
      #pragma unroll
      for (int r = 0; r < 4; ++r) {
        qp[mt][r][0] += __shfl_xor(qp[mt][r][0], off);
        qp[mt][r][1] += __shfl_xor(qp[mt][r][1], off);
      }
  }
  float* qb = (float*)(smem + 36864);   // [4][32][2]
  if (l15 == 0) {
    #pragma unroll
    for (int mt = 0; mt < 2; ++mt)
      #pragma unroll
      for (int r = 0; r < 4; ++r) {
        int row = mt * 16 + lg * 4 + r;
        qb[(w * 32 + row) * 2 + 0] = qp[mt][r][0];
        qb[(w * 32 + row) * 2 + 1] = qp[mt][r][1];
      }
  }
  __syncthreads();
  if (tid < 64) {
    int row = tid >> 1, c = tid & 1;
    float sum = qb[row * 2 + c] + qb[(32 + row) * 2 + c] +
                qb[(64 + row) * 2 + c] + qb[(96 + row) * 2 + c];
    float q = fast_tanh(sum + b2[c]);
    int m = m0 + row;
    int tt = m / 1280;
    int o = m - tt * 1280;
    int base = (o * 16 + tt) * 2;
    out[base + c] = q;
    out[NOUT + base + c] = q + wstd[c] * gauss_eps(base + c);
  }
}

extern "C" void kernel_launch(void* const* d_in, const int* in_sizes, int n_in,
                              void* d_out, int out_size, void* d_ws, size_t ws_size,
                              hipStream_t stream) {
  const float* frames = (const float*)d_in[0];
  const float* digits = (const float*)d_in[1];
  const float* W1   = (const float*)d_in[3];
  const float* b1   = (const float*)d_in[4];
  const float* W2   = (const float*)d_in[5];
  const float* b2   = (const float*)d_in[6];
  const float* wstd = (const float*)d_in[7];
  uint8_t* conv_ws = (uint8_t*)d_ws;                          // [20480][2816B] f16
  uint8_t* w1t     = conv_ws + (size_t)20480 * CROWB;         // [256][2816B] f16
  float* out = (float*)d_out;

  prep_w1t<<<dim3(88), dim3(256), 0, stream>>>(W1, w1t);
  conv_mfma<<<dim3(2048), dim3(256), 0, stream>>>(frames, digits, conv_ws);
  mlp_mfma<<<dim3(640), dim3(256), 0, stream>>>(conv_ws, w1t, b1, W2, b2, wstd, out);
}